// Round 5
// baseline (374.092 us; speedup 1.0000x reference)
//
#include <hip/hip_runtime.h>

#define NB   4
#define C_IN 256
#define CQD  64
#define NPT  4096
#define L2E  1.44269504088896f

typedef __attribute__((ext_vector_type(8))) short bf16x8;
typedef __attribute__((ext_vector_type(4))) short bf16x4;
typedef __attribute__((ext_vector_type(4))) float f32x4;
typedef unsigned short u16;
typedef unsigned int   u32;

#define EXP2F(x)      __builtin_amdgcn_exp2f(x)
#define MFMA16(A,B,C) __builtin_amdgcn_mfma_f32_16x16x16bf16_1k(A,B,C,0,0,0)
#define MFMA32(A,B,C) __builtin_amdgcn_mfma_f32_16x16x32_bf16(A,B,C,0,0,0)

__device__ __forceinline__ u16 f2bf(float f) {          // RNE (cold paths)
    u32 u = __float_as_uint(f);
    u += 0x7fff + ((u >> 16) & 1);
    return (u16)(u >> 16);
}
// one v_perm: (bf16_trunc(hi)<<16) | bf16_trunc(lo)
__device__ __forceinline__ u32 pack_trunc(float lo, float hi) {
    return __builtin_amdgcn_perm(__float_as_uint(hi), __float_as_uint(lo), 0x07060302u);
}

// ---------------------------------------------------------------------------
// prep: pack wq|wk|wv into bf16 wbf[384][256], biases into bias[384]
// ---------------------------------------------------------------------------
__global__ void prep_kernel(
    const float* __restrict__ wq, const float* __restrict__ bq,
    const float* __restrict__ wk, const float* __restrict__ bk,
    const float* __restrict__ wv, const float* __restrict__ bv,
    u16* __restrict__ wbf, float* __restrict__ bias)
{
    const int gid = blockIdx.x*256 + threadIdx.x;
    if (gid < 384*256) {
        const int r = gid >> 8, c = gid & 255;
        const float v = (r < 64) ? wq[r*256 + c]
                      : (r < 128) ? wk[(r-64)*256 + c]
                                  : wv[(r-128)*256 + c];
        wbf[gid] = f2bf(v);
    } else if (gid < 384*256 + 384) {
        const int r = gid - 384*256;
        bias[r] = (r < 64) ? bq[r] : (r < 128) ? bk[r-64] : bv[r-128];
    }
}

// ---------------------------------------------------------------------------
// proj: MFMA pointwise projections, x read ONCE. Wave w owns tiles T=4*ot+w
// (output rows 16T..16T+15). Epilogue staged via LDS for coalesced stores.
// grid (N/32, B), block 256.
// ---------------------------------------------------------------------------
union ProjShared {
    u16 x_t[32][264];                            // [n][c] bf16, stride 528B
    struct { u16 qk[32][136]; u16 vl[256][40]; } ep;
};

__global__ __launch_bounds__(256) void proj_kernel(
    const float* __restrict__ x, const u16* __restrict__ wbf,
    const float* __restrict__ bias,
    u16* __restrict__ qT, u16* __restrict__ kT, u16* __restrict__ vbf)
{
    __shared__ ProjShared sh;

    const int t  = threadIdx.x;
    const int n0 = blockIdx.x * 32;
    const int b  = blockIdx.y;

    {   // stage x tile transposed -> bf16 LDS
        const int ln = t & 31;
        const int cg = t >> 5;
        #pragma unroll
        for (int rr = 0; rr < 8; rr++) {
            const int c = 4*cg + 32*rr;
            const float f0 = x[((size_t)(b*C_IN + c+0))*NPT + n0 + ln];
            const float f1 = x[((size_t)(b*C_IN + c+1))*NPT + n0 + ln];
            const float f2 = x[((size_t)(b*C_IN + c+2))*NPT + n0 + ln];
            const float f3 = x[((size_t)(b*C_IN + c+3))*NPT + n0 + ln];
            ushort4 u4;
            u4.x = f2bf(f0); u4.y = f2bf(f1); u4.z = f2bf(f2); u4.w = f2bf(f3);
            *(ushort4*)&sh.x_t[ln][c] = u4;
        }
    }
    __syncthreads();

    const int w = t >> 6, l = t & 63, q = l >> 4, c16 = l & 15;

    f32x4 acc[6][2];
    #pragma unroll
    for (int ot = 0; ot < 6; ot++)
        #pragma unroll
        for (int nt = 0; nt < 2; nt++)
            acc[ot][nt] = (f32x4){0.f, 0.f, 0.f, 0.f};

    #pragma unroll
    for (int kk = 0; kk < 8; kk++) {
        const bf16x8 bf0 = *(const bf16x8*)&sh.x_t[c16     ][kk*32 + 8*q];
        const bf16x8 bf1 = *(const bf16x8*)&sh.x_t[16 + c16][kk*32 + 8*q];
        #pragma unroll
        for (int ot = 0; ot < 6; ot++) {
            const int o = 16*(4*ot + w) + c16;
            const bf16x8 af = *(const bf16x8*)&wbf[(size_t)o*C_IN + kk*32 + 8*q];
            acc[ot][0] = MFMA32(af, bf0, acc[ot][0]);
            acc[ot][1] = MFMA32(af, bf1, acc[ot][1]);
        }
    }
    __syncthreads();   // x_t dead; reuse LDS for epilogue staging

    // stage q/k (ot 0,1 -> rows 0..127) and v (ot 2..5 -> rows 128..383)
    #pragma unroll
    for (int ot = 0; ot < 6; ot++) {
        const int T  = 4*ot + w;
        const int ob = 16*T + 4*q;
        float b0 = bias[ob+0], b1 = bias[ob+1], b2 = bias[ob+2], b3 = bias[ob+3];
        #pragma unroll
        for (int nt = 0; nt < 2; nt++) {
            const f32x4 a = acc[ot][nt];
            const float v0 = a[0]+b0, v1 = a[1]+b1, v2 = a[2]+b2, v3 = a[3]+b3;
            if (ot < 2) {
                uint2 u;
                u.x = (u32)f2bf(v0) | ((u32)f2bf(v1) << 16);
                u.y = (u32)f2bf(v2) | ((u32)f2bf(v3) << 16);
                *(uint2*)&sh.ep.qk[16*nt + c16][16*T + 4*q] = u;
            } else {
                const int cb = 16*T - 128 + 4*q;
                sh.ep.vl[cb+0][16*nt + c16] = f2bf(v0);
                sh.ep.vl[cb+1][16*nt + c16] = f2bf(v1);
                sh.ep.vl[cb+2][16*nt + c16] = f2bf(v2);
                sh.ep.vl[cb+3][16*nt + c16] = f2bf(v3);
            }
        }
    }
    __syncthreads();

    {   // coalesced global stores
        const int n  = t >> 3;
        const int o8 = (t & 7) * 8;
        *(uint4*)&qT[((size_t)b*NPT + n0 + n)*CQD + o8] = *(uint4*)&sh.ep.qk[n][o8];
        *(uint4*)&kT[((size_t)b*NPT + n0 + n)*CQD + o8] = *(uint4*)&sh.ep.qk[n][64 + o8];
        u16* vrow = &vbf[((size_t)b*C_IN + t)*NPT + n0];
        #pragma unroll
        for (int j = 0; j < 4; j++)
            *(uint4*)&vrow[8*j] = *(uint4*)&sh.ep.vl[t][8*j];
    }
}

// ---------------------------------------------------------------------------
// stats: no-max partial softmax sums over 1024-wide m-split via MFMA.
// Z = sum exp2(s*L2E)  (|s| << 88, no overflow possible)
// grid (4 msplit, N/64, B), block 256.
// ---------------------------------------------------------------------------
__global__ __launch_bounds__(256) void stats_kernel(
    const u16* __restrict__ qT, const u16* __restrict__ kT,
    float* __restrict__ psum)
{
    const int t = threadIdx.x;
    const int w = t >> 6, l = t & 63, q = l >> 4, c16 = l & 15;
    const int ms = blockIdx.x, nt = blockIdx.y, b = blockIdx.z;
    const int nb = nt*64 + 16*w;

    const bf16x8* qp = (const bf16x8*)&qT[((size_t)b*NPT + nb + c16)*CQD + 8*q];
    const bf16x8 aq0 = qp[0];
    const bf16x8 aq1 = qp[4];

    float rz[4] = {0.f, 0.f, 0.f, 0.f};

    for (int m0 = ms*1024; m0 < ms*1024 + 1024; m0 += 64) {
        f32x4 s[4];
        #pragma unroll
        for (int mj = 0; mj < 4; mj++) {
            const bf16x8* kp = (const bf16x8*)&kT[((size_t)b*NPT + m0 + 16*mj + c16)*CQD + 8*q];
            f32x4 a = {0.f, 0.f, 0.f, 0.f};
            a = MFMA32(aq0, kp[0], a);
            a = MFMA32(aq1, kp[4], a);
            s[mj] = a;
        }
        #pragma unroll
        for (int r = 0; r < 4; r++) {
            rz[r] += EXP2F(s[0][r]*L2E) + EXP2F(s[1][r]*L2E)
                   + EXP2F(s[2][r]*L2E) + EXP2F(s[3][r]*L2E);
        }
    }
    #pragma unroll
    for (int r = 0; r < 4; r++) {
        float Z = rz[r];
        #pragma unroll
        for (int d = 1; d < 16; d <<= 1) Z += __shfl_xor(Z, d, 64);
        if (c16 == 0)
            psum[((size_t)(b*4 + ms))*NPT + nb + 4*q + r] = Z;
    }
}

// ---------------------------------------------------------------------------
// merge: Lrow[n] = log2(sum of 4 partial Z)
// ---------------------------------------------------------------------------
__global__ void merge_kernel(const float* __restrict__ psum, float* __restrict__ Lrow)
{
    const int g = blockIdx.x*256 + threadIdx.x;
    const int b = g >> 12;
    const int n = g & 4095;
    float Z = 0.f;
    #pragma unroll
    for (int s = 0; s < 4; s++) Z += psum[((size_t)(b*4+s))*NPT + n];
    Lrow[(size_t)b*NPT + n] = __log2f(Z);
}

// ---------------------------------------------------------------------------
// attn: barrier-free main loop. Waves partition n' (wave w owns stripes
// 64*nt+16w..+15). s via 16x16x32 MFMA; p stays in registers (C-layout ==
// 16x16x16 B-layout); PV via 16x16x16 MFMA. End: LDS cross-wave reduction,
// out = gamma*o + x.  grid 1024 flat (XCD-swizzled), block 256.
// ---------------------------------------------------------------------------
__global__ __launch_bounds__(256, 3) void attn_kernel(
    const u16* __restrict__ qT, const u16* __restrict__ kT, const u16* __restrict__ vbf,
    const float* __restrict__ Lrow, const float* __restrict__ gamma,
    const float* __restrict__ x, float* __restrict__ out)
{
    __shared__ f32x4 red[4][2][4][16][5];   // [ci][mjl][wave][c16][q(+pad)] 40KB

    const int t = threadIdx.x;
    const int w = t >> 6, l = t & 63, q = l >> 4, c16 = l & 15;

    // XCD swizzle: consecutive ids round-robin XCDs; give each XCD 2 (b,cs)
    // pairs so its L2 holds few v/q slabs. Correctness-independent.
    const int id   = blockIdx.x;
    const int pair = ((id & 7) << 1) | ((id >> 9) & 1);
    const int mt   = (id >> 3) & 63;
    const int b    = pair >> 2, cs = pair & 3;
    const int m0   = mt * 64;

    // k B-fragments in registers for the whole n sweep (32 VGPRs)
    bf16x8 kf[4][2];
    #pragma unroll
    for (int mj = 0; mj < 4; mj++) {
        const bf16x8* kp = (const bf16x8*)&kT[((size_t)b*NPT + m0 + 16*mj + c16)*CQD + 8*q];
        kf[mj][0] = kp[0];
        kf[mj][1] = kp[4];
    }

    f32x4 acc[4][4];   // [ci][mj] partial over this wave's n'
    #pragma unroll
    for (int ci = 0; ci < 4; ci++)
        #pragma unroll
        for (int mj = 0; mj < 4; mj++)
            acc[ci][mj] = (f32x4){0.f, 0.f, 0.f, 0.f};

    const u16*  qrow = &qT[((size_t)b*NPT + 16*w + c16)*CQD + 8*q];
    const float* Lb  = &Lrow[(size_t)b*NPT + 16*w + 4*q];
    const u16*  vb   = &vbf[((size_t)(b*C_IN + cs*64 + c16))*NPT + 16*w + 4*q];

    bf16x8 qa0 = *(const bf16x8*)qrow;
    bf16x8 qa1 = *(const bf16x8*)(qrow + 32);

    for (int nt = 0; nt < 64; nt++) {
        const int n0 = nt * 64;

        // s: wave's 16 n' rows x 64 m
        f32x4 s[4];
        #pragma unroll
        for (int mj = 0; mj < 4; mj++) {
            f32x4 a = {0.f, 0.f, 0.f, 0.f};
            a = MFMA32(qa0, kf[mj][0], a);
            a = MFMA32(qa1, kf[mj][1], a);
            s[mj] = a;
        }
        if (nt < 63) {   // prefetch next q fragment
            qa0 = *(const bf16x8*)(qrow + (size_t)(n0 + 64)*CQD);
            qa1 = *(const bf16x8*)(qrow + (size_t)(n0 + 64)*CQD + 32);
        }
        // v A-fragments (independent of s; scheduler hoists above exp chain)
        bf16x4 va[4];
        #pragma unroll
        for (int ci = 0; ci < 4; ci++)
            va[ci] = *(const bf16x4*)(vb + (size_t)(16*ci)*NPT + n0);

        const float4 Lr = *(const float4*)(Lb + n0);

        // p = exp2(s*L2E - Lrow); trunc-pack straight into B-fragments
        #pragma unroll
        for (int mj = 0; mj < 4; mj++) {
            const float p0 = EXP2F(s[mj][0]*L2E - Lr.x);
            const float p1 = EXP2F(s[mj][1]*L2E - Lr.y);
            const float p2 = EXP2F(s[mj][2]*L2E - Lr.z);
            const float p3 = EXP2F(s[mj][3]*L2E - Lr.w);
            uint2 u;
            u.x = pack_trunc(p0, p1);
            u.y = pack_trunc(p2, p3);
            const bf16x4 pf = *(bf16x4*)&u;
            #pragma unroll
            for (int ci = 0; ci < 4; ci++)
                acc[ci][mj] = MFMA16(va[ci], pf, acc[ci][mj]);
        }
    }

    // cross-wave reduction over n' partitions + fused residual epilogue
    const float g = gamma[0];
    #pragma unroll
    for (int ph = 0; ph < 2; ph++) {
        if (ph) __syncthreads();
        #pragma unroll
        for (int ci = 0; ci < 4; ci++)
            #pragma unroll
            for (int mjl = 0; mjl < 2; mjl++)
                red[ci][mjl][w][c16][q] = acc[ci][2*ph + mjl];
        __syncthreads();
        #pragma unroll
        for (int mjl = 0; mjl < 2; mjl++) {
            const int mj = 2*ph + mjl;
            f32x4 sum = red[w][mjl][0][c16][q];
            sum += red[w][mjl][1][c16][q];
            sum += red[w][mjl][2][c16][q];
            sum += red[w][mjl][3][c16][q];
            #pragma unroll
            for (int r = 0; r < 4; r++) {
                const size_t o = ((size_t)(b*C_IN + cs*64 + 16*w + 4*q + r))*NPT
                               + m0 + 16*mj + c16;
                out[o] = g*sum[r] + x[o];
            }
        }
    }
}

// ---------------------------------------------------------------------------
extern "C" void kernel_launch(void* const* d_in, const int* in_sizes, int n_in,
                              void* d_out, int out_size, void* d_ws, size_t ws_size,
                              hipStream_t stream)
{
    const float* x     = (const float*)d_in[0];
    const float* wq    = (const float*)d_in[1];
    const float* bq    = (const float*)d_in[2];
    const float* wk    = (const float*)d_in[3];
    const float* bk    = (const float*)d_in[4];
    const float* wv    = (const float*)d_in[5];
    const float* bv    = (const float*)d_in[6];
    const float* gamma = (const float*)d_in[7];
    float* out = (float*)d_out;

    u16* qT  = (u16*)d_ws;                              // 2 MB
    u16* kT  = qT  + (size_t)NB*NPT*CQD;                // 2 MB
    u16* vbf = kT  + (size_t)NB*NPT*CQD;                // 8 MB
    u16* wbf = vbf + (size_t)NB*C_IN*NPT;               // 192 KB
    float* fp    = (float*)(wbf + 384*256);
    float* bias  = fp;                                  // 384
    float* psum  = bias + 384;                          // 64 KB
    float* Lrow  = psum + (size_t)NB*4*NPT;             // 64 KB

    prep_kernel<<<dim3(386), 256, 0, stream>>>(wq, bq, wk, bk, wv, bv, wbf, bias);
    proj_kernel<<<dim3(NPT/32, NB), 256, 0, stream>>>(x, wbf, bias, qT, kT, vbf);
    stats_kernel<<<dim3(4, NPT/64, NB), 256, 0, stream>>>(qT, kT, psum);
    merge_kernel<<<dim3(64), 256, 0, stream>>>(psum, Lrow);
    attn_kernel<<<dim3(1024), 256, 0, stream>>>(qT, kT, vbf, Lrow, gamma, x, out);
}

// Round 6
// 287.118 us; speedup vs baseline: 1.3029x; 1.3029x over previous
//
#include <hip/hip_runtime.h>

#define NB   4
#define C_IN 256
#define CQD  64
#define NPT  4096
#define L2E  1.44269504088896f

typedef __attribute__((ext_vector_type(8))) short bf16x8;
typedef __attribute__((ext_vector_type(4))) float f32x4;
typedef unsigned short u16;
typedef unsigned int   u32;

#define EXP2F(x)      __builtin_amdgcn_exp2f(x)
#define MFMA32(A,B,C) __builtin_amdgcn_mfma_f32_16x16x32_bf16(A,B,C,0,0,0)

__device__ __forceinline__ u16 f2bf(float f) {          // RNE (cold paths)
    u32 u = __float_as_uint(f);
    u += 0x7fff + ((u >> 16) & 1);
    return (u16)(u >> 16);
}
// one v_perm: (bf16_trunc(hi)<<16) | bf16_trunc(lo)
__device__ __forceinline__ u32 pack_trunc(float lo, float hi) {
    return __builtin_amdgcn_perm(__float_as_uint(hi), __float_as_uint(lo), 0x07060302u);
}

// ---------------------------------------------------------------------------
// prep: pack wq|wk|wv into bf16 wbf[384][256], biases into bias[384]
// ---------------------------------------------------------------------------
__global__ void prep_kernel(
    const float* __restrict__ wq, const float* __restrict__ bq,
    const float* __restrict__ wk, const float* __restrict__ bk,
    const float* __restrict__ wv, const float* __restrict__ bv,
    u16* __restrict__ wbf, float* __restrict__ bias)
{
    const int gid = blockIdx.x*256 + threadIdx.x;
    if (gid < 384*256) {
        const int r = gid >> 8, c = gid & 255;
        const float v = (r < 64) ? wq[r*256 + c]
                      : (r < 128) ? wk[(r-64)*256 + c]
                                  : wv[(r-128)*256 + c];
        wbf[gid] = f2bf(v);
    } else if (gid < 384*256 + 384) {
        const int r = gid - 384*256;
        bias[r] = (r < 64) ? bq[r] : (r < 128) ? bk[r-64] : bv[r-128];
    }
}

// ---------------------------------------------------------------------------
// proj: MFMA pointwise projections, x read ONCE. Wave w owns tiles T=4*ot+w.
// grid (N/32, B), block 256.
// ---------------------------------------------------------------------------
union ProjShared {
    u16 x_t[32][264];                            // [n][c] bf16, stride 528B
    struct { u16 qk[32][136]; u16 vl[256][40]; } ep;
};

__global__ __launch_bounds__(256) void proj_kernel(
    const float* __restrict__ x, const u16* __restrict__ wbf,
    const float* __restrict__ bias,
    u16* __restrict__ qT, u16* __restrict__ kT, u16* __restrict__ vbf)
{
    __shared__ ProjShared sh;

    const int t  = threadIdx.x;
    const int n0 = blockIdx.x * 32;
    const int b  = blockIdx.y;

    {   // stage x tile transposed -> bf16 LDS
        const int ln = t & 31;
        const int cg = t >> 5;
        #pragma unroll
        for (int rr = 0; rr < 8; rr++) {
            const int c = 4*cg + 32*rr;
            const float f0 = x[((size_t)(b*C_IN + c+0))*NPT + n0 + ln];
            const float f1 = x[((size_t)(b*C_IN + c+1))*NPT + n0 + ln];
            const float f2 = x[((size_t)(b*C_IN + c+2))*NPT + n0 + ln];
            const float f3 = x[((size_t)(b*C_IN + c+3))*NPT + n0 + ln];
            ushort4 u4;
            u4.x = f2bf(f0); u4.y = f2bf(f1); u4.z = f2bf(f2); u4.w = f2bf(f3);
            *(ushort4*)&sh.x_t[ln][c] = u4;
        }
    }
    __syncthreads();

    const int w = t >> 6, l = t & 63, q = l >> 4, c16 = l & 15;

    f32x4 acc[6][2];
    #pragma unroll
    for (int ot = 0; ot < 6; ot++)
        #pragma unroll
        for (int nt = 0; nt < 2; nt++)
            acc[ot][nt] = (f32x4){0.f, 0.f, 0.f, 0.f};

    #pragma unroll
    for (int kk = 0; kk < 8; kk++) {
        const bf16x8 bf0 = *(const bf16x8*)&sh.x_t[c16     ][kk*32 + 8*q];
        const bf16x8 bf1 = *(const bf16x8*)&sh.x_t[16 + c16][kk*32 + 8*q];
        #pragma unroll
        for (int ot = 0; ot < 6; ot++) {
            const int o = 16*(4*ot + w) + c16;
            const bf16x8 af = *(const bf16x8*)&wbf[(size_t)o*C_IN + kk*32 + 8*q];
            acc[ot][0] = MFMA32(af, bf0, acc[ot][0]);
            acc[ot][1] = MFMA32(af, bf1, acc[ot][1]);
        }
    }
    __syncthreads();   // x_t dead; reuse LDS for epilogue staging

    #pragma unroll
    for (int ot = 0; ot < 6; ot++) {
        const int T  = 4*ot + w;
        const int ob = 16*T + 4*q;
        float b0 = bias[ob+0], b1 = bias[ob+1], b2 = bias[ob+2], b3 = bias[ob+3];
        #pragma unroll
        for (int nt = 0; nt < 2; nt++) {
            const f32x4 a = acc[ot][nt];
            const float v0 = a[0]+b0, v1 = a[1]+b1, v2 = a[2]+b2, v3 = a[3]+b3;
            if (ot < 2) {
                uint2 u;
                u.x = (u32)f2bf(v0) | ((u32)f2bf(v1) << 16);
                u.y = (u32)f2bf(v2) | ((u32)f2bf(v3) << 16);
                *(uint2*)&sh.ep.qk[16*nt + c16][16*T + 4*q] = u;
            } else {
                const int cb = 16*T - 128 + 4*q;
                sh.ep.vl[cb+0][16*nt + c16] = f2bf(v0);
                sh.ep.vl[cb+1][16*nt + c16] = f2bf(v1);
                sh.ep.vl[cb+2][16*nt + c16] = f2bf(v2);
                sh.ep.vl[cb+3][16*nt + c16] = f2bf(v3);
            }
        }
    }
    __syncthreads();

    {   // coalesced global stores
        const int n  = t >> 3;
        const int o8 = (t & 7) * 8;
        *(uint4*)&qT[((size_t)b*NPT + n0 + n)*CQD + o8] = *(uint4*)&sh.ep.qk[n][o8];
        *(uint4*)&kT[((size_t)b*NPT + n0 + n)*CQD + o8] = *(uint4*)&sh.ep.qk[n][64 + o8];
        u16* vrow = &vbf[((size_t)b*C_IN + t)*NPT + n0];
        #pragma unroll
        for (int j = 0; j < 4; j++)
            *(uint4*)&vrow[8*j] = *(uint4*)&sh.ep.vl[t][8*j];
    }
}

// ---------------------------------------------------------------------------
// stats: no-max partial softmax sums over 1024-wide m-split via MFMA.
// grid (4 msplit, N/64, B), block 256.
// ---------------------------------------------------------------------------
__global__ __launch_bounds__(256) void stats_kernel(
    const u16* __restrict__ qT, const u16* __restrict__ kT,
    float* __restrict__ psum)
{
    const int t = threadIdx.x;
    const int w = t >> 6, l = t & 63, q = l >> 4, c16 = l & 15;
    const int ms = blockIdx.x, nt = blockIdx.y, b = blockIdx.z;
    const int nb = nt*64 + 16*w;

    const bf16x8* qp = (const bf16x8*)&qT[((size_t)b*NPT + nb + c16)*CQD + 8*q];
    const bf16x8 aq0 = qp[0];
    const bf16x8 aq1 = qp[4];

    float rz[4] = {0.f, 0.f, 0.f, 0.f};

    for (int m0 = ms*1024; m0 < ms*1024 + 1024; m0 += 64) {
        f32x4 s[4];
        #pragma unroll
        for (int mj = 0; mj < 4; mj++) {
            const bf16x8* kp = (const bf16x8*)&kT[((size_t)b*NPT + m0 + 16*mj + c16)*CQD + 8*q];
            f32x4 a = {0.f, 0.f, 0.f, 0.f};
            a = MFMA32(aq0, kp[0], a);
            a = MFMA32(aq1, kp[4], a);
            s[mj] = a;
        }
        #pragma unroll
        for (int r = 0; r < 4; r++) {
            rz[r] += EXP2F(s[0][r]*L2E) + EXP2F(s[1][r]*L2E)
                   + EXP2F(s[2][r]*L2E) + EXP2F(s[3][r]*L2E);
        }
    }
    #pragma unroll
    for (int r = 0; r < 4; r++) {
        float Z = rz[r];
        #pragma unroll
        for (int d = 1; d < 16; d <<= 1) Z += __shfl_xor(Z, d, 64);
        if (c16 == 0)
            psum[((size_t)(b*4 + ms))*NPT + nb + 4*q + r] = Z;
    }
}

// ---------------------------------------------------------------------------
// merge: Lrow[n] = log2(sum of 4 partial Z)
// ---------------------------------------------------------------------------
__global__ void merge_kernel(const float* __restrict__ psum, float* __restrict__ Lrow)
{
    const int g = blockIdx.x*256 + threadIdx.x;
    const int b = g >> 12;
    const int n = g & 4095;
    float Z = 0.f;
    #pragma unroll
    for (int s = 0; s < 4; s++) Z += psum[((size_t)(b*4+s))*NPT + n];
    Lrow[(size_t)b*NPT + n] = __log2f(Z);
}

// ---------------------------------------------------------------------------
// attn: K=32 PV with LDS p in a conflict-engineered flat layout.
// p unit U(wv,qv,c16m,mj) = (wv*16+qv*4+mj)*17 + c16m : uint2 = p rows
// n'=16wv+4qv+r, col m=16mj+c16m. Writes 4-way banked (cheap), reads 2-way
// (free). One barrier/iter, double-buffered. Wave w owns c rows 16w..16w+15
// (v 1x amplification). grid 1024 flat (XCD-swizzled), block 256.
// ---------------------------------------------------------------------------
__global__ __launch_bounds__(256, 4) void attn_kernel(
    const u16* __restrict__ qT, const u16* __restrict__ kT, const u16* __restrict__ vbf,
    const float* __restrict__ Lrow, const float* __restrict__ gamma,
    const float* __restrict__ x, float* __restrict__ out)
{
    __shared__ uint2 p_l[2][1088];   // 2 x 8704 B

    const int t = threadIdx.x;
    const int w = t >> 6, l = t & 63, q = l >> 4, c16 = l & 15;

    const int id   = blockIdx.x;
    const int pair = ((id & 7) << 1) | ((id >> 9) & 1);
    const int mt   = (id >> 3) & 63;
    const int b    = pair >> 2, cs = pair & 3;
    const int m0   = mt * 64;

    // k B-fragments in registers for the whole n sweep
    bf16x8 kf[4][2];
    #pragma unroll
    for (int mj = 0; mj < 4; mj++) {
        const bf16x8* kp = (const bf16x8*)&kT[((size_t)b*NPT + m0 + 16*mj + c16)*CQD + 8*q];
        kf[mj][0] = kp[0];
        kf[mj][1] = kp[4];
    }

    f32x4 acc[4];   // [mj]: c = cs*64 + 16w + 4q + r, m = m0 + 16mj + c16
    #pragma unroll
    for (int mj = 0; mj < 4; mj++) acc[mj] = (f32x4){0.f, 0.f, 0.f, 0.f};

    const u16*  qrow = &qT[((size_t)b*NPT + 16*w + c16)*CQD + 8*q];
    const float* Lb  = &Lrow[(size_t)b*NPT + 16*w + 4*q];
    const u16*  vrow = &vbf[((size_t)(b*C_IN + cs*64 + 16*w + c16))*NPT + 8*q];

    // LDS unit indices
    const int Uw  = (w*16 + q*4)*17 + c16;                    // + mj*17
    const int Ur0 = ((q>>1)*16 + (q&1)*8)*17 + c16;           // h=0, + mj*17
    const int Ur1 = Ur0 + 32*17;                              // h=1

    bf16x8 qa0 = *(const bf16x8*)qrow;
    bf16x8 qa1 = *(const bf16x8*)(qrow + 32);

    int buf = 0;
    for (int nt = 0; nt < 64; nt++) {
        const int n0 = nt * 64;

        // s: wave's 16 n' rows x 64 m
        f32x4 s[4];
        #pragma unroll
        for (int mj = 0; mj < 4; mj++) {
            f32x4 a = {0.f, 0.f, 0.f, 0.f};
            a = MFMA32(qa0, kf[mj][0], a);
            a = MFMA32(qa1, kf[mj][1], a);
            s[mj] = a;
        }
        if (nt < 63) {   // prefetch next q fragment
            qa0 = *(const bf16x8*)(qrow + (size_t)(n0 + 64)*CQD);
            qa1 = *(const bf16x8*)(qrow + (size_t)(n0 + 64)*CQD + 32);
        }
        // v A-fragments for both 32-n' halves (issued before barrier)
        const bf16x8 va0 = *(const bf16x8*)(vrow + n0);
        const bf16x8 va1 = *(const bf16x8*)(vrow + n0 + 32);

        const float4 Lr = *(const float4*)(Lb + n0);

        // p = exp2(s*L2E - Lrow), trunc-pack, store flat units
        #pragma unroll
        for (int mj = 0; mj < 4; mj++) {
            const float p0 = EXP2F(s[mj][0]*L2E - Lr.x);
            const float p1 = EXP2F(s[mj][1]*L2E - Lr.y);
            const float p2 = EXP2F(s[mj][2]*L2E - Lr.z);
            const float p3 = EXP2F(s[mj][3]*L2E - Lr.w);
            uint2 u;
            u.x = pack_trunc(p0, p1);
            u.y = pack_trunc(p2, p3);
            p_l[buf][Uw + mj*17] = u;
        }
        __syncthreads();

        // PV: two K=32 MFMAs per mj (halves h=0,1)
        #pragma unroll
        for (int mj = 0; mj < 4; mj++) {
            const uint2 a0 = p_l[buf][Ur0 + mj*17];
            const uint2 a1 = p_l[buf][Ur0 + mj*17 + 68];
            const uint2 b0 = p_l[buf][Ur1 + mj*17];
            const uint2 b1 = p_l[buf][Ur1 + mj*17 + 68];
            uint4 fa = make_uint4(a0.x, a0.y, a1.x, a1.y);
            uint4 fb = make_uint4(b0.x, b0.y, b1.x, b1.y);
            acc[mj] = MFMA32(va0, *(bf16x8*)&fa, acc[mj]);
            acc[mj] = MFMA32(va1, *(bf16x8*)&fb, acc[mj]);
        }
        buf ^= 1;
    }

    const float g = gamma[0];
    #pragma unroll
    for (int mj = 0; mj < 4; mj++)
        #pragma unroll
        for (int r = 0; r < 4; r++) {
            const size_t o = ((size_t)(b*C_IN + cs*64 + 16*w + 4*q + r))*NPT
                           + m0 + 16*mj + c16;
            out[o] = g*acc[mj][r] + x[o];
        }
}

// ---------------------------------------------------------------------------
extern "C" void kernel_launch(void* const* d_in, const int* in_sizes, int n_in,
                              void* d_out, int out_size, void* d_ws, size_t ws_size,
                              hipStream_t stream)
{
    const float* x     = (const float*)d_in[0];
    const float* wq    = (const float*)d_in[1];
    const float* bq    = (const float*)d_in[2];
    const float* wk    = (const float*)d_in[3];
    const float* bk    = (const float*)d_in[4];
    const float* wv    = (const float*)d_in[5];
    const float* bv    = (const float*)d_in[6];
    const float* gamma = (const float*)d_in[7];
    float* out = (float*)d_out;

    u16* qT  = (u16*)d_ws;                              // 2 MB
    u16* kT  = qT  + (size_t)NB*NPT*CQD;                // 2 MB
    u16* vbf = kT  + (size_t)NB*NPT*CQD;                // 8 MB
    u16* wbf = vbf + (size_t)NB*C_IN*NPT;               // 192 KB
    float* fp    = (float*)(wbf + 384*256);
    float* bias  = fp;                                  // 384
    float* psum  = bias + 384;                          // 64 KB
    float* Lrow  = psum + (size_t)NB*4*NPT;             // 64 KB

    prep_kernel<<<dim3(386), 256, 0, stream>>>(wq, bq, wk, bk, wv, bv, wbf, bias);
    proj_kernel<<<dim3(NPT/32, NB), 256, 0, stream>>>(x, wbf, bias, qT, kT, vbf);
    stats_kernel<<<dim3(4, NPT/64, NB), 256, 0, stream>>>(qT, kT, psum);
    merge_kernel<<<dim3(64), 256, 0, stream>>>(psum, Lrow);
    attn_kernel<<<dim3(1024), 256, 0, stream>>>(qT, kT, vbf, Lrow, gamma, x, out);
}